// Round 1
// baseline (2802.585 us; speedup 1.0000x reference)
//
#include <hip/hip_runtime.h>

#define B_ 128
#define T_ 2048
#define H_ 128
#define IN_ 6
#define GRP_ 8                  // steps per inner group
#define NGRP_ (T_ / GRP_)       // 256
#define CHUNK_ 32               // steps per flag chunk
#define NCHUNK_ (T_ / CHUNK_)   // 64
#define FLAG_STRIDE_ 64         // uints between flags (256B)
#define HS_ 144                 // LDS row stride in shorts

typedef _Float16 f16x8 __attribute__((ext_vector_type(8)));
typedef float    f32x4 __attribute__((ext_vector_type(4)));

__device__ __forceinline__ unsigned short f2h_u(float f) {
  union { _Float16 h; unsigned short u; } v; v.h = (_Float16)f; return v.u;
}
__device__ __forceinline__ unsigned int pack2(float a, float b) {
  return (unsigned int)f2h_u(a) | ((unsigned int)f2h_u(b) << 16);
}
__device__ __forceinline__ float sigf_(float x) {
  return __builtin_amdgcn_rcpf(1.0f + __expf(-x));
}
__device__ __forceinline__ float tanhf_(float x) {
  return 2.0f * __builtin_amdgcn_rcpf(1.0f + __expf(-2.0f * x)) - 1.0f;
}
__device__ __forceinline__ f16x8 load_w8(const float* __restrict__ p) {
  f16x8 r;
#pragma unroll
  for (int i = 0; i < 8; ++i) r[i] = (_Float16)p[i];
  return r;
}

__global__ void init_flags(unsigned int* flags) {
  flags[blockIdx.x * 256 + threadIdx.x] = 0u;  // grid 12 -> 3072 = 48 flags * 64
}

// ---------------------------------------------------------------------------
// R13: fuse the input GEMM into the recurrence WGs — the fp32 xg ring (1 GiB
// written + 1 GiB read, 32 KB/step through each consumer CU's L1) was the
// slowest pipeline stage. Now 24 WGs total (layer=bid>>3, bg=bid&7).
// Layer l>0 stages the f16 h_in of layer l-1 from `region` into LDS
// (double-buffered 8-step groups, reg-staged prefetch one group ahead) and
// computes gates = bias + Wih.h_in[t] + Whh.h[t-1] in one 8-deep MFMA chain.
// Flags: fh 0-7 (layer0 h chunks), fh 8-15 (layer1 h chunks). No fx/fc.
// Region reuse unchanged: layer l reads positions ahead of its own writes;
// layer l+1 reads only after the release flag.
// ---------------------------------------------------------------------------
__global__ __launch_bounds__(512, 2)
void lstm_pipe(const float* __restrict__ x,
               const float* __restrict__ Wih0, const float* __restrict__ Whh0,
               const float* __restrict__ bih0, const float* __restrict__ bhh0,
               const float* __restrict__ Wih1, const float* __restrict__ Whh1,
               const float* __restrict__ bih1, const float* __restrict__ bhh1,
               const float* __restrict__ Wih2, const float* __restrict__ Whh2,
               const float* __restrict__ bih2, const float* __restrict__ bhh2,
               unsigned short* __restrict__ region,   // f16 [B][T][128]
               unsigned int* __restrict__ state_h,    // [B][64] f16x2
               unsigned int* __restrict__ flags)
{
  const int bid  = blockIdx.x;
  const int tid  = threadIdx.x;
  const int lane = tid & 63;
  const int wv   = tid >> 6;    // wave 0..7
  const int n16  = lane & 15;
  const int quad = lane >> 4;

  // hstate: [2][16][HS_] shorts; sbuf (layers 1/2): [2][8][16][HS_] shorts.
  __shared__ unsigned short smem[(2 * 16 + 2 * GRP_ * 16) * HS_];  // 82944 B
  __shared__ int s_have;

#define WAITP(ptr_, need_, have_)                                   \
  do {                                                              \
    if ((have_) < (need_)) {                                        \
      if (tid == 0) {                                               \
        int v = (int)__hip_atomic_load(ptr_, __ATOMIC_RELAXED,      \
                                       __HIP_MEMORY_SCOPE_AGENT);   \
        while (v < (need_)) {                                       \
          __builtin_amdgcn_s_sleep(2);                              \
          v = (int)__hip_atomic_load(ptr_, __ATOMIC_RELAXED,        \
                                     __HIP_MEMORY_SCOPE_AGENT);     \
        }                                                           \
        (void)__hip_atomic_load(ptr_, __ATOMIC_ACQUIRE,             \
                                __HIP_MEMORY_SCOPE_AGENT);          \
        s_have = v;                                                 \
      }                                                             \
      __syncthreads();                                              \
      (have_) = s_have;                                             \
    }                                                               \
  } while (0)

  const int layer = bid >> 3;
  const int bg    = bid & 7;
  const float* Whh = (layer == 0) ? Whh0 : ((layer == 1) ? Whh1 : Whh2);

  unsigned short* hstate = smem;                  // [2][16][HS_]
  unsigned short* xb = smem + 2 * 16 * HS_;       // [8][16][8] (layer 0 only)

  f16x8 whh[4][4];
#pragma unroll
  for (int j = 0; j < 4; ++j)
#pragma unroll
    for (int kc = 0; kc < 4; ++kc)
      whh[j][kc] = load_w8(Whh + (size_t)(j * 128 + 16 * wv + n16) * H_ + kc * 32 + quad * 8);

  for (int i = tid; i < (2 * 16 * HS_) / 2; i += 512) ((unsigned int*)smem)[i] = 0u;

  f32x4 c4 = {0.f, 0.f, 0.f, 0.f};
  unsigned int d0[GRP_], d1[GRP_];
  unsigned int* fh_out = (layer < 2) ? &flags[(layer * 8 + bg) * FLAG_STRIDE_] : nullptr;

  if (layer == 0) {
    // ------------------------- layer 0 ---------------------------------
    const float* Wih = Wih0;
    f32x4 bias4[4];
#pragma unroll
    for (int j = 0; j < 4; ++j)
#pragma unroll
      for (int r = 0; r < 4; ++r) {
        int row = j * 128 + 16 * wv + quad * 4 + r;
        bias4[j][r] = bih0[row] + bhh0[row];
      }
    f16x8 wx[4];
#pragma unroll
    for (int j = 0; j < 4; ++j)
#pragma unroll
      for (int i = 0; i < 8; ++i) wx[j][i] = (_Float16)0.f;
    if (quad == 0) {
#pragma unroll
      for (int j = 0; j < 4; ++j) {
        const float* p = Wih + (size_t)(j * 128 + 16 * wv + n16) * IN_;
#pragma unroll
        for (int i = 0; i < IN_; ++i) wx[j][i] = (_Float16)p[i];
      }
    }
    const f32x4 z4 = {0.f, 0.f, 0.f, 0.f};
    const int sn_x = tid >> 3, st_x = tid & 7;
    uint4 xreg = {0u, 0u, 0u, 0u};
    __syncthreads();
    if (tid < 128) {
      const float* xp = x + ((size_t)(bg * 16 + sn_x) * T_ + st_x) * IN_;
      xreg.x = pack2(xp[0], xp[1]); xreg.y = pack2(xp[2], xp[3]);
      xreg.z = pack2(xp[4], xp[5]); xreg.w = 0u;
      *(uint4*)&xb[(st_x * 16 + sn_x) * 8] = xreg;
    }
    __syncthreads();

    for (int g = 0; g < NGRP_; ++g) {
      int gs = (g + 1 < NGRP_) ? (g + 1) : g;
      if (tid < 128) {
        const float* xp = x + ((size_t)(bg * 16 + sn_x) * T_ + (8 * gs + st_x)) * IN_;
        xreg.x = pack2(xp[0], xp[1]); xreg.y = pack2(xp[2], xp[3]);
        xreg.z = pack2(xp[4], xp[5]); xreg.w = 0u;
      }
#pragma unroll
      for (int s = 0; s < GRP_; ++s) {
        const int rp = s & 1, wp = rp ^ 1;
        f16x8 hs[4];
#pragma unroll
        for (int kc = 0; kc < 4; ++kc)
          hs[kc] = *(const f16x8*)&hstate[(rp * 16 + n16) * HS_ + kc * 32 + quad * 8];
        f16x8 xi;
#pragma unroll
        for (int i = 0; i < 8; ++i) xi[i] = (_Float16)0.f;
        if (quad == 0) xi = *(const f16x8*)&xb[(s * 16 + n16) * 8];
        f32x4 acc[4];
#pragma unroll
        for (int j = 0; j < 4; ++j) {
          f32x4 aw = bias4[j];
#pragma unroll
          for (int kc = 0; kc < 4; ++kc)
            aw = __builtin_amdgcn_mfma_f32_16x16x32_f16(whh[j][kc], hs[kc], aw, 0, 0, 0);
          f32x4 ai = __builtin_amdgcn_mfma_f32_16x16x32_f16(wx[j], xi, z4, 0, 0, 0);
#pragma unroll
          for (int r = 0; r < 4; ++r) acc[j][r] = aw[r] + ai[r];
        }
        float hv4[4];
#pragma unroll
        for (int r = 0; r < 4; ++r) {
          float i_ = sigf_(acc[0][r]);
          float f_ = sigf_(acc[1][r]);
          float g_ = tanhf_(acc[2][r]);
          float o_ = sigf_(acc[3][r]);
          float cc = f_ * c4[r] + i_ * g_;
          c4[r] = cc;
          hv4[r] = o_ * tanhf_(cc);
        }
        unsigned int u0 = pack2(hv4[0], hv4[1]);
        unsigned int u1 = pack2(hv4[2], hv4[3]);
        d0[s] = u0; d1[s] = u1;
        uint2 hw; hw.x = u0; hw.y = u1;
        *(uint2*)&hstate[(wp * 16 + n16) * HS_ + 16 * wv + quad * 4] = hw;
        __syncthreads();
      }
      // deferred h stores + next-group x staging
#pragma unroll
      for (int s = 0; s < GRP_; ++s) {
        size_t off = ((size_t)(bg * 16 + n16) * T_ + (8 * g + s)) * H_ + 16 * wv + quad * 4;
        uint2 hw; hw.x = d0[s]; hw.y = d1[s];
        *(uint2*)(region + off) = hw;
      }
      if (tid < 128) *(uint4*)&xb[(st_x * 16 + sn_x) * 8] = xreg;
      __syncthreads();  // drains region stores + publishes xb
      if (((8 * (g + 1)) % CHUNK_) == 0 && tid == 0)
        __hip_atomic_store(fh_out, (unsigned int)((8 * (g + 1)) / CHUNK_),
                           __ATOMIC_RELEASE, __HIP_MEMORY_SCOPE_AGENT);
    }
  } else {
    // --------------- layers 1 and 2: fused GEMM + recurrence -----------
    const float* Wih  = (layer == 1) ? Wih1 : Wih2;
    const float* bihl = (layer == 1) ? bih1 : bih2;
    const float* bhhl = (layer == 1) ? bhh1 : bhh2;
    unsigned int* fh_in = &flags[((layer - 1) * 8 + bg) * FLAG_STRIDE_];

    f16x8 wih[4][4];
#pragma unroll
    for (int j = 0; j < 4; ++j)
#pragma unroll
      for (int kc = 0; kc < 4; ++kc)
        wih[j][kc] = load_w8(Wih + (size_t)(j * 128 + 16 * wv + n16) * H_ + kc * 32 + quad * 8);
    f32x4 bias4[4];
#pragma unroll
    for (int j = 0; j < 4; ++j)
#pragma unroll
      for (int r = 0; r < 4; ++r) {
        int row = j * 128 + 16 * wv + quad * 4 + r;
        bias4[j][r] = bihl[row] + bhhl[row];
      }

    unsigned short* sbuf = smem + 2 * 16 * HS_;   // [2][8][16][HS_]
    // staging map: thread -> (t within group, batch row, 64B segment)
    const int srow = tid >> 2;          // 0..127
    const int st_t = srow >> 4;         // 0..7
    const int st_b = srow & 15;         // 0..15
    const int sseg = tid & 3;           // 4 x uint4 each
    const uint4* greg_base = (const uint4*)(region + (size_t)(bg * 16 + st_b) * T_ * H_);

    int have_h = 0;
    uint4 sreg[4];
    // prologue: stage group 0 into buffer 0
    WAITP(fh_in, 1, have_h);
    {
      const uint4* gp = greg_base + (size_t)st_t * (H_ / 8) + sseg * 4;
#pragma unroll
      for (int i = 0; i < 4; ++i) sreg[i] = gp[i];
      uint4* lp = (uint4*)&sbuf[(st_t * 16 + st_b) * HS_] + sseg * 4;
#pragma unroll
      for (int i = 0; i < 4; ++i) lp[i] = sreg[i];
    }
    __syncthreads();  // hstate zeros + buf0 visible

    for (int g = 0; g < NGRP_; ++g) {
      const int pb = g & 1;
      // issue next-group staging loads early (land at group end)
      if (g + 1 < NGRP_) {
        if (((g + 1) & 3) == 0) WAITP(fh_in, ((g + 1) >> 2) + 1, have_h);
        const uint4* gp = greg_base + (size_t)(8 * (g + 1) + st_t) * (H_ / 8) + sseg * 4;
#pragma unroll
        for (int i = 0; i < 4; ++i) sreg[i] = gp[i];
      }
#pragma unroll
      for (int s = 0; s < GRP_; ++s) {
        const int rp = s & 1, wp = rp ^ 1;
        f16x8 hs[4], hi[4];
#pragma unroll
        for (int kc = 0; kc < 4; ++kc) {
          hs[kc] = *(const f16x8*)&hstate[(rp * 16 + n16) * HS_ + kc * 32 + quad * 8];
          hi[kc] = *(const f16x8*)&sbuf[(pb * 128 + s * 16 + n16) * HS_ + kc * 32 + quad * 8];
        }
        f32x4 acc[4];
#pragma unroll
        for (int j = 0; j < 4; ++j) {
          f32x4 a = bias4[j];
#pragma unroll
          for (int kc = 0; kc < 4; ++kc)
            a = __builtin_amdgcn_mfma_f32_16x16x32_f16(wih[j][kc], hi[kc], a, 0, 0, 0);
#pragma unroll
          for (int kc = 0; kc < 4; ++kc)
            a = __builtin_amdgcn_mfma_f32_16x16x32_f16(whh[j][kc], hs[kc], a, 0, 0, 0);
          acc[j] = a;
        }
        float hv4[4];
#pragma unroll
        for (int r = 0; r < 4; ++r) {
          float i_ = sigf_(acc[0][r]);
          float f_ = sigf_(acc[1][r]);
          float g_ = tanhf_(acc[2][r]);
          float o_ = sigf_(acc[3][r]);
          float cc = f_ * c4[r] + i_ * g_;
          c4[r] = cc;
          hv4[r] = o_ * tanhf_(cc);
        }
        unsigned int u0 = pack2(hv4[0], hv4[1]);
        unsigned int u1 = pack2(hv4[2], hv4[3]);
        d0[s] = u0; d1[s] = u1;
        uint2 hw; hw.x = u0; hw.y = u1;
        *(uint2*)&hstate[(wp * 16 + n16) * HS_ + 16 * wv + quad * 4] = hw;
        __syncthreads();
      }
      // group end: write prefetched group to the other LDS buffer
      if (g + 1 < NGRP_) {
        uint4* lp = (uint4*)&sbuf[(((g + 1) & 1) * 128 + st_t * 16 + st_b) * HS_] + sseg * 4;
#pragma unroll
        for (int i = 0; i < 4; ++i) lp[i] = sreg[i];
      }
      if (layer == 1) {
#pragma unroll
        for (int s = 0; s < GRP_; ++s) {
          size_t off = ((size_t)(bg * 16 + n16) * T_ + (8 * g + s)) * H_ + 16 * wv + quad * 4;
          uint2 hw; hw.x = d0[s]; hw.y = d1[s];
          *(uint2*)(region + off) = hw;
        }
      }
      __syncthreads();  // drains region stores + publishes sbuf writes
      if (layer == 1 && ((g & 3) == 3) && tid == 0)
        __hip_atomic_store(fh_out, (unsigned int)((g >> 2) + 1),
                           __ATOMIC_RELEASE, __HIP_MEMORY_SCOPE_AGENT);
    }
    if (layer == 2) {
      state_h[(bg * 16 + n16) * 64 + 8 * wv + 2 * quad]     = d0[GRP_ - 1];
      state_h[(bg * 16 + n16) * 64 + 8 * wv + 2 * quad + 1] = d1[GRP_ - 1];
    }
  }
#undef WAITP
}

// ---------------------------------------------------------------------------
__global__ void head_kernel(const unsigned int* __restrict__ state_h,
                            const float* __restrict__ Wout,
                            const float* __restrict__ bout,
                            float* __restrict__ out)
{
  int b = threadIdx.x;  // 128 threads, 1 block
  float s = bout[0];
  for (int j = 0; j < 64; ++j) {
    unsigned int p = state_h[b * 64 + j];
    union { unsigned short u; _Float16 h; } lo, hi;
    lo.u = (unsigned short)(p & 0xffffu);
    hi.u = (unsigned short)(p >> 16);
    s += (float)lo.h * Wout[2 * j] + (float)hi.h * Wout[2 * j + 1];
  }
  out[b] = s;
}

// ---------------------------------------------------------------------------
extern "C" void kernel_launch(void* const* d_in, const int* in_sizes, int n_in,
                              void* d_out, int out_size, void* d_ws, size_t ws_size,
                              hipStream_t stream)
{
  const float* x = (const float*)d_in[0];
  const float* Wih[3] = {(const float*)d_in[1], (const float*)d_in[5], (const float*)d_in[9]};
  const float* Whh[3] = {(const float*)d_in[2], (const float*)d_in[6], (const float*)d_in[10]};
  const float* bih[3] = {(const float*)d_in[3], (const float*)d_in[7], (const float*)d_in[11]};
  const float* bhh[3] = {(const float*)d_in[4], (const float*)d_in[8], (const float*)d_in[12]};
  const float* Wout = (const float*)d_in[13];
  const float* bout = (const float*)d_in[14];
  float* out = (float*)d_out;

  char* ws = (char*)d_ws;
  size_t off = 0;
  unsigned short* region = (unsigned short*)(ws + off); off += (size_t)B_ * T_ * H_ * 2;   // 64 MiB
  unsigned int* state_h  = (unsigned int*)(ws + off);   off += (size_t)B_ * 64 * 4;
  off = (off + 255) & ~(size_t)255;
  unsigned int* flags    = (unsigned int*)(ws + off);   off += 48 * FLAG_STRIDE_ * 4;

  init_flags<<<12, 256, 0, stream>>>(flags);
  lstm_pipe<<<24, 512, 0, stream>>>(x,
      Wih[0], Whh[0], bih[0], bhh[0],
      Wih[1], Whh[1], bih[1], bhh[1],
      Wih[2], Whh[2], bih[2], bhh[2],
      region, state_h, flags);
  head_kernel<<<1, 128, 0, stream>>>(state_h, Wout, bout, out);
}

// Round 2
// 1790.250 us; speedup vs baseline: 1.5655x; 1.5655x over previous
//
#include <hip/hip_runtime.h>

#define B_ 128
#define T_ 2048
#define H_ 128
#define IN_ 6
#define GRP_ 8                  // steps per inner group
#define NGRP_ (T_ / GRP_)       // 256
#define CHUNK_ 32               // steps per flag chunk
#define NCHUNK_ (T_ / CHUNK_)   // 64
#define FLAG_STRIDE_ 64         // uints between flags (256B)
#define HS_ 144                 // LDS row stride in shorts
#define XGRING_ 3               // xg ring depth (chunks)
#define XGSLOT_ (CHUNK_ * 8192) // floats per ring slot

typedef _Float16 f16x8 __attribute__((ext_vector_type(8)));
typedef float    f32x4 __attribute__((ext_vector_type(4)));

__device__ __forceinline__ unsigned short f2h_u(float f) {
  union { _Float16 h; unsigned short u; } v; v.h = (_Float16)f; return v.u;
}
__device__ __forceinline__ unsigned int pack2(float a, float b) {
  return (unsigned int)f2h_u(a) | ((unsigned int)f2h_u(b) << 16);
}
__device__ __forceinline__ float sigf_(float x) {
  return __builtin_amdgcn_rcpf(1.0f + __expf(-x));
}
__device__ __forceinline__ float tanhf_(float x) {
  return 2.0f * __builtin_amdgcn_rcpf(1.0f + __expf(-2.0f * x)) - 1.0f;
}
__device__ __forceinline__ f16x8 load_w8(const float* __restrict__ p) {
  f16x8 r;
#pragma unroll
  for (int i = 0; i < 8; ++i) r[i] = (_Float16)p[i];
  return r;
}

__global__ void init_flags(unsigned int* flags) {
  flags[blockIdx.x * 256 + threadIdx.x] = 0u;  // grid 20 -> 5120 = 80 flags * 64
}

// ---------------------------------------------------------------------------
// R14: back to the R0 split-GEMM pipeline (R1 proved xg traffic was hidden;
// fusing put 16 MFMA + conflicted LDS reads on the serial chain). New here:
//  (a) batch-8 recurrence WGs (48 rec WGs) with column-mirrored MFMA operands:
//      B cols 8-15 duplicate 0-7 (same LDS address -> broadcast), C-init
//      likewise, so D col b == D col b+8. Lane n16<8 handles r={0,1}, lane
//      n16>=8 handles r={2,3}: activation issue per SIMD halves at ZERO
//      redistribution cost (the dominant ~880cy/step VALU phase -> ~440).
//  (b) XOR swizzle (byte ^= (row&7)<<4) on hstate + GEMM h-staging LDS:
//      kills the stride-288B b128 bank conflicts (~200cy/step).
// GEMM producers stay batch-16 (16 WGs, 9x slack), wait on two half-flags.
// Flags: fh[l][bgg] 0-31, fx[gl][bg] 32-47, fc[gl][bgg] 48-79.
// ---------------------------------------------------------------------------
__global__ __launch_bounds__(512, 2)
void lstm_pipe(const float* __restrict__ x,
               const float* __restrict__ Wih0, const float* __restrict__ Whh0,
               const float* __restrict__ bih0, const float* __restrict__ bhh0,
               const float* __restrict__ Wih1, const float* __restrict__ Whh1,
               const float* __restrict__ bih1, const float* __restrict__ bhh1,
               const float* __restrict__ Wih2, const float* __restrict__ Whh2,
               const float* __restrict__ bih2, const float* __restrict__ bhh2,
               unsigned short* __restrict__ region,   // f16 [B][T][128]
               float* __restrict__ xg,                // fp32 rings [2][8][3][XGSLOT_]
               unsigned int* __restrict__ state_h,    // [B][64] f16x2
               unsigned int* __restrict__ flags)
{
  const int bid  = blockIdx.x;
  const int tid  = threadIdx.x;
  const int lane = tid & 63;
  const int wv   = tid >> 6;    // wave 0..7
  const int n16  = lane & 15;
  const int quad = lane >> 4;
  const int bcol = n16 & 7;     // batch column within the 8-batch slice
  const int hh   = n16 >> 3;    // r-half this lane owns (rec role)

  __shared__ unsigned short smem[32 * 16 * HS_];   // 147456 B
  __shared__ int s_have;

#define WAITP(ptr_, need_, have_)                                   \
  do {                                                              \
    if ((have_) < (need_)) {                                        \
      if (tid == 0) {                                               \
        int v = (int)__hip_atomic_load(ptr_, __ATOMIC_RELAXED,      \
                                       __HIP_MEMORY_SCOPE_AGENT);   \
        while (v < (need_)) {                                       \
          __builtin_amdgcn_s_sleep(2);                              \
          v = (int)__hip_atomic_load(ptr_, __ATOMIC_RELAXED,        \
                                     __HIP_MEMORY_SCOPE_AGENT);     \
        }                                                           \
        (void)__hip_atomic_load(ptr_, __ATOMIC_ACQUIRE,             \
                                __HIP_MEMORY_SCOPE_AGENT);          \
        s_have = v;                                                 \
      }                                                             \
      __syncthreads();                                              \
      (have_) = s_have;                                             \
    }                                                               \
  } while (0)

  if (bid >= 48) {
    // ======================= GEMM producer role ==========================
    const int gi = bid - 48;
    const int gl = 1 + (gi >> 3);
    const int bg = gi & 7;
    const float* Wih = (gl == 1) ? Wih1 : Wih2;
    const float* bih = (gl == 1) ? bih1 : bih2;
    const float* bhh = (gl == 1) ? bhh1 : bhh2;
    float* xgo = xg + (size_t)((gl - 1) * 8 + bg) * (XGRING_ * (size_t)XGSLOT_);
    unsigned int* fhA = &flags[((gl - 1) * 16 + 2 * bg)     * FLAG_STRIDE_];
    unsigned int* fhB = &flags[((gl - 1) * 16 + 2 * bg + 1) * FLAG_STRIDE_];
    unsigned int* fx_out = &flags[(32 + (gl - 1) * 8 + bg) * FLAG_STRIDE_];
    unsigned int* fcA = &flags[(48 + (gl - 1) * 16 + 2 * bg)     * FLAG_STRIDE_];
    unsigned int* fcB = &flags[(48 + (gl - 1) * 16 + 2 * bg + 1) * FLAG_STRIDE_];

    f16x8 wih[4][4];
#pragma unroll
    for (int j = 0; j < 4; ++j)
#pragma unroll
      for (int kc = 0; kc < 4; ++kc)
        wih[j][kc] = load_w8(Wih + (size_t)(j * 128 + 16 * wv + n16) * H_ + kc * 32 + quad * 8);
    f32x4 bias4[4];
#pragma unroll
    for (int j = 0; j < 4; ++j)
#pragma unroll
      for (int r = 0; r < 4; ++r) {
        int row = j * 128 + 16 * wv + quad * 4 + r;
        bias4[j][r] = bih[row] + bhh[row];
      }

    int haveA = 0, haveB = 0, havecA = 0, havecB = 0;
    const int tt = tid >> 4, bb = tid & 15;  // h-chunk staging map (1 thread/row)
    const int swk = bb & 7;                  // write-side swizzle key
    for (int k = 0; k < NCHUNK_; ++k) {
      WAITP(fhA, k + 1, haveA);
      WAITP(fhB, k + 1, haveB);
      if (k >= XGRING_) {
        WAITP(fcA, k - (XGRING_ - 1), havecA);
        WAITP(fcB, k - (XGRING_ - 1), havecB);
      }
      // stage h chunk [32][16][128] -> LDS, swizzled by batch row
      {
        const uint4* gp = (const uint4*)(region +
            ((size_t)(bg * 16 + bb) * T_ + (size_t)(CHUNK_ * k + tt)) * H_);
        uint4* lp = (uint4*)&smem[(tt * 16 + bb) * HS_];
#pragma unroll
        for (int i = 0; i < 16; ++i) lp[i ^ swk] = gp[i];
      }
      __syncthreads();
      const int slot = k % XGRING_;
      for (int t = 0; t < CHUNK_; ++t) {
        f16x8 hi[4];
#pragma unroll
        for (int kc = 0; kc < 4; ++kc)
          hi[kc] = *(const f16x8*)&smem[(t * 16 + n16) * HS_ +
                                        ((kc * 32 + quad * 8) ^ (bcol << 3))];
        float* xp = xgo + (size_t)(slot * CHUNK_ + t) * 8192 + quad * 64 + n16 * 4;
#pragma unroll
        for (int j = 0; j < 4; ++j) {
          f32x4 a = bias4[j];
#pragma unroll
          for (int kc = 0; kc < 4; ++kc)
            a = __builtin_amdgcn_mfma_f32_16x16x32_f16(wih[j][kc], hi[kc], a, 0, 0, 0);
          *(f32x4*)(xp + (size_t)(8 * j + wv) * 256) = a;
        }
      }
      __syncthreads();  // drains stores + protects LDS reuse
      if (tid == 0)
        __hip_atomic_store(fx_out, (unsigned int)(k + 1),
                           __ATOMIC_RELEASE, __HIP_MEMORY_SCOPE_AGENT);
    }
    return;
  }

  // ========================= Recurrence role =============================
  const int layer = bid >> 4;
  const int bgg   = bid & 15;          // batch-8 slice 0..15
  const int bg    = bgg >> 1;
  const int half  = bgg & 1;
  const int batch = bg * 16 + half * 8 + bcol;
  const float* Whh = (layer == 0) ? Whh0 : ((layer == 1) ? Whh1 : Whh2);

  unsigned short* hstate = smem;                 // [2][8][HS_]
  unsigned short* xb = smem + 2 * 8 * HS_;       // [8][8][8] (layer 0 only)

  f16x8 whh[4][4];
#pragma unroll
  for (int j = 0; j < 4; ++j)
#pragma unroll
    for (int kc = 0; kc < 4; ++kc)
      whh[j][kc] = load_w8(Whh + (size_t)(j * 128 + 16 * wv + n16) * H_ + kc * 32 + quad * 8);

  for (int i = tid; i < (2 * 8 * HS_) / 2; i += 512) ((unsigned int*)smem)[i] = 0u;

  float c20 = 0.f, c21 = 0.f;
  unsigned int dh[GRP_];
  unsigned int* fh_out = (layer < 2) ? &flags[(layer * 16 + bgg) * FLAG_STRIDE_] : nullptr;
  const int hu_idx = (8 * wv + 2 * quad + hh) ^ (bcol << 2);  // swizzled uint col
  const int hcol   = 16 * wv + 4 * quad + 2 * hh;             // h-index of dh pair

  if (layer == 0) {
    // ------------------------- layer 0 ---------------------------------
    f32x4 bias4[4];
#pragma unroll
    for (int j = 0; j < 4; ++j)
#pragma unroll
      for (int r = 0; r < 4; ++r) {
        int row = j * 128 + 16 * wv + quad * 4 + r;
        bias4[j][r] = bih0[row] + bhh0[row];
      }
    f16x8 wx[4];
#pragma unroll
    for (int j = 0; j < 4; ++j)
#pragma unroll
      for (int i = 0; i < 8; ++i) wx[j][i] = (_Float16)0.f;
    if (quad == 0) {
#pragma unroll
      for (int j = 0; j < 4; ++j) {
        const float* p = Wih0 + (size_t)(j * 128 + 16 * wv + n16) * IN_;
#pragma unroll
        for (int i = 0; i < IN_; ++i) wx[j][i] = (_Float16)p[i];
      }
    }
    const f32x4 z4 = {0.f, 0.f, 0.f, 0.f};
    const int sn_x = tid & 7, st_x = tid >> 3;  // valid for tid<64
    uint4 xreg = {0u, 0u, 0u, 0u};
    __syncthreads();
    if (tid < 64) {
      const float* xp = x + ((size_t)(bg * 16 + half * 8 + sn_x) * T_ + st_x) * IN_;
      xreg.x = pack2(xp[0], xp[1]); xreg.y = pack2(xp[2], xp[3]);
      xreg.z = pack2(xp[4], xp[5]); xreg.w = 0u;
      *(uint4*)&xb[(st_x * 8 + sn_x) * 8] = xreg;
    }
    __syncthreads();

    for (int g = 0; g < NGRP_; ++g) {
      int gs = (g + 1 < NGRP_) ? (g + 1) : g;
      if (tid < 64) {
        const float* xp = x + ((size_t)(bg * 16 + half * 8 + sn_x) * T_ + (8 * gs + st_x)) * IN_;
        xreg.x = pack2(xp[0], xp[1]); xreg.y = pack2(xp[2], xp[3]);
        xreg.z = pack2(xp[4], xp[5]); xreg.w = 0u;
      }
#pragma unroll
      for (int s = 0; s < GRP_; ++s) {
        const int rp = s & 1, wp = rp ^ 1;
        f16x8 hs[4];
#pragma unroll
        for (int kc = 0; kc < 4; ++kc)
          hs[kc] = *(const f16x8*)&hstate[(rp * 8 + bcol) * HS_ +
                                          ((kc * 32 + quad * 8) ^ (bcol << 3))];
        f16x8 xi;
#pragma unroll
        for (int i = 0; i < 8; ++i) xi[i] = (_Float16)0.f;
        if (quad == 0) xi = *(const f16x8*)&xb[(s * 8 + bcol) * 8];
        f32x4 acc[4];
#pragma unroll
        for (int j = 0; j < 4; ++j) {
          f32x4 aw = bias4[j];
#pragma unroll
          for (int kc = 0; kc < 4; ++kc)
            aw = __builtin_amdgcn_mfma_f32_16x16x32_f16(whh[j][kc], hs[kc], aw, 0, 0, 0);
          f32x4 ai = __builtin_amdgcn_mfma_f32_16x16x32_f16(wx[j], xi, z4, 0, 0, 0);
#pragma unroll
          for (int r = 0; r < 4; ++r) acc[j][r] = aw[r] + ai[r];
        }
        float ga[4], gb[4];
#pragma unroll
        for (int j = 0; j < 4; ++j) {
          ga[j] = hh ? acc[j][2] : acc[j][0];
          gb[j] = hh ? acc[j][3] : acc[j][1];
        }
        float i0 = sigf_(ga[0]), f0 = sigf_(ga[1]), t0 = tanhf_(ga[2]), o0 = sigf_(ga[3]);
        c20 = f0 * c20 + i0 * t0;
        float h0 = o0 * tanhf_(c20);
        float i1 = sigf_(gb[0]), f1 = sigf_(gb[1]), t1 = tanhf_(gb[2]), o1 = sigf_(gb[3]);
        c21 = f1 * c21 + i1 * t1;
        float h1 = o1 * tanhf_(c21);
        unsigned int u = pack2(h0, h1);
        dh[s] = u;
        ((unsigned int*)&hstate[(wp * 8 + bcol) * HS_])[hu_idx] = u;
        __syncthreads();
      }
      // deferred h stores + next-group x staging
#pragma unroll
      for (int s = 0; s < GRP_; ++s) {
        size_t off = ((size_t)batch * T_ + (8 * g + s)) * H_ + hcol;
        *(unsigned int*)(region + off) = dh[s];
      }
      if (tid < 64) *(uint4*)&xb[(st_x * 8 + sn_x) * 8] = xreg;
      __syncthreads();  // drains region stores + publishes xb
      if (((g & 3) == 3) && tid == 0)
        __hip_atomic_store(fh_out, (unsigned int)((g >> 2) + 1),
                           __ATOMIC_RELEASE, __HIP_MEMORY_SCOPE_AGENT);
    }
  } else {
    // ----------------------- layers 1 and 2 ----------------------------
    const float* xgi = xg + (size_t)((layer - 1) * 8 + bg) * (XGRING_ * (size_t)XGSLOT_);
    const int xcol = half * 8 + bcol;   // real batch column in the xg tile
    f32x4 xr[2][4];
    auto load_xg = [&](int t, int buf) {
      int slot = (t >> 5) % XGRING_;
      const float* p = xgi + (size_t)(slot * CHUNK_ + (t & 31)) * 8192
                       + (size_t)wv * 256 + quad * 64 + xcol * 4;
      xr[buf][0] = *(const f32x4*)(p);
      xr[buf][1] = *(const f32x4*)(p + 2048);
      xr[buf][2] = *(const f32x4*)(p + 4096);
      xr[buf][3] = *(const f32x4*)(p + 6144);
    };
    unsigned int* fx_in  = &flags[(32 + (layer - 1) * 8 + bg) * FLAG_STRIDE_];
    unsigned int* fc_out = &flags[(48 + (layer - 1) * 16 + bgg) * FLAG_STRIDE_];
    int have_x = 0;
    __syncthreads();  // hstate zeros visible

    for (int g = 0; g < NGRP_; ++g) {
      if ((g & 3) == 0) {
        int c = g >> 2;
        WAITP(fx_in, c + 1, have_x);
        load_xg(32 * c, 0);
        load_xg(32 * c + 1, 1);
      }
#pragma unroll
      for (int s = 0; s < GRP_; ++s) {
        const int t = 8 * g + s;
        const int rp = s & 1, wp = rp ^ 1;
        f16x8 hs[4];
#pragma unroll
        for (int kc = 0; kc < 4; ++kc)
          hs[kc] = *(const f16x8*)&hstate[(rp * 8 + bcol) * HS_ +
                                          ((kc * 32 + quad * 8) ^ (bcol << 3))];
        f32x4 ci[4];
#pragma unroll
        for (int j = 0; j < 4; ++j) ci[j] = xr[s & 1][j];
        if (!(((g & 3) == 3) && s >= 6)) load_xg(t + 2, s & 1);
        f32x4 acc[4];
#pragma unroll
        for (int j = 0; j < 4; ++j) {
          f32x4 aw = ci[j];
#pragma unroll
          for (int kc = 0; kc < 4; ++kc)
            aw = __builtin_amdgcn_mfma_f32_16x16x32_f16(whh[j][kc], hs[kc], aw, 0, 0, 0);
          acc[j] = aw;
        }
        float ga[4], gb[4];
#pragma unroll
        for (int j = 0; j < 4; ++j) {
          ga[j] = hh ? acc[j][2] : acc[j][0];
          gb[j] = hh ? acc[j][3] : acc[j][1];
        }
        float i0 = sigf_(ga[0]), f0 = sigf_(ga[1]), t0 = tanhf_(ga[2]), o0 = sigf_(ga[3]);
        c20 = f0 * c20 + i0 * t0;
        float h0 = o0 * tanhf_(c20);
        float i1 = sigf_(gb[0]), f1 = sigf_(gb[1]), t1 = tanhf_(gb[2]), o1 = sigf_(gb[3]);
        c21 = f1 * c21 + i1 * t1;
        float h1 = o1 * tanhf_(c21);
        unsigned int u = pack2(h0, h1);
        dh[s] = u;
        ((unsigned int*)&hstate[(wp * 8 + bcol) * HS_])[hu_idx] = u;
        __syncthreads();
      }
      if (layer == 1) {
#pragma unroll
        for (int s = 0; s < GRP_; ++s) {
          size_t off = ((size_t)batch * T_ + (8 * g + s)) * H_ + hcol;
          *(unsigned int*)(region + off) = dh[s];
        }
        __syncthreads();  // drain h stores before fh publish
      }
      if (((g & 3) == 3) && tid == 0) {
        unsigned int cdone = (unsigned int)((g >> 2) + 1);
        if (layer == 1)
          __hip_atomic_store(fh_out, cdone, __ATOMIC_RELEASE, __HIP_MEMORY_SCOPE_AGENT);
        __hip_atomic_store(fc_out, cdone, __ATOMIC_RELEASE, __HIP_MEMORY_SCOPE_AGENT);
      }
    }
    if (layer == 2)
      state_h[(size_t)batch * 64 + (8 * wv + 2 * quad + hh)] = dh[GRP_ - 1];
  }
#undef WAITP
}

// ---------------------------------------------------------------------------
__global__ void head_kernel(const unsigned int* __restrict__ state_h,
                            const float* __restrict__ Wout,
                            const float* __restrict__ bout,
                            float* __restrict__ out)
{
  int b = threadIdx.x;  // 128 threads, 1 block
  float s = bout[0];
  for (int j = 0; j < 64; ++j) {
    unsigned int p = state_h[b * 64 + j];
    union { unsigned short u; _Float16 h; } lo, hi;
    lo.u = (unsigned short)(p & 0xffffu);
    hi.u = (unsigned short)(p >> 16);
    s += (float)lo.h * Wout[2 * j] + (float)hi.h * Wout[2 * j + 1];
  }
  out[b] = s;
}

// ---------------------------------------------------------------------------
extern "C" void kernel_launch(void* const* d_in, const int* in_sizes, int n_in,
                              void* d_out, int out_size, void* d_ws, size_t ws_size,
                              hipStream_t stream)
{
  const float* x = (const float*)d_in[0];
  const float* Wih[3] = {(const float*)d_in[1], (const float*)d_in[5], (const float*)d_in[9]};
  const float* Whh[3] = {(const float*)d_in[2], (const float*)d_in[6], (const float*)d_in[10]};
  const float* bih[3] = {(const float*)d_in[3], (const float*)d_in[7], (const float*)d_in[11]};
  const float* bhh[3] = {(const float*)d_in[4], (const float*)d_in[8], (const float*)d_in[12]};
  const float* Wout = (const float*)d_in[13];
  const float* bout = (const float*)d_in[14];
  float* out = (float*)d_out;

  char* ws = (char*)d_ws;
  size_t off = 0;
  unsigned short* region = (unsigned short*)(ws + off); off += (size_t)B_ * T_ * H_ * 2;   // 64 MiB
  float* xg = (float*)(ws + off);                       off += (size_t)16 * XGRING_ * XGSLOT_ * 4;  // 48 MiB
  unsigned int* state_h  = (unsigned int*)(ws + off);   off += (size_t)B_ * 64 * 4;
  off = (off + 255) & ~(size_t)255;
  unsigned int* flags    = (unsigned int*)(ws + off);   off += 80 * FLAG_STRIDE_ * 4;

  init_flags<<<20, 256, 0, stream>>>(flags);
  lstm_pipe<<<64, 512, 0, stream>>>(x,
      Wih[0], Whh[0], bih[0], bhh[0],
      Wih[1], Whh[1], bih[1], bhh[1],
      Wih[2], Whh[2], bih[2], bhh[2],
      region, xg, state_h, flags);
  head_kernel<<<1, 128, 0, stream>>>(state_h, Wout, bout, out);
}

// Round 4
// 1540.799 us; speedup vs baseline: 1.8189x; 1.1619x over previous
//
#include <hip/hip_runtime.h>

#define B_ 128
#define T_ 2048
#define H_ 128
#define IN_ 6
#define GRP_ 8                  // steps per inner group
#define NGRP_ (T_ / GRP_)       // 256
#define CHUNK_ 32               // steps per flag chunk
#define NCHUNK_ (T_ / CHUNK_)   // 64
#define FLAG_STRIDE_ 64         // uints between flags (256B)
#define HS_ 144                 // LDS row stride in shorts
#define XGRING_ 3               // xg ring depth (chunks)
#define XGSLOT_ (CHUNK_ * 8192) // floats per ring slot
#define NSLICE_ 32              // batch-4 slices per layer
#define NFLAGS_ 144             // fh 0-63, fx 64-79, fc 80-143

typedef _Float16 f16x8 __attribute__((ext_vector_type(8)));
typedef float    f32x4 __attribute__((ext_vector_type(4)));

__device__ __forceinline__ unsigned short f2h_u(float f) {
  union { _Float16 h; unsigned short u; } v; v.h = (_Float16)f; return v.u;
}
__device__ __forceinline__ unsigned int pack2(float a, float b) {
  return (unsigned int)f2h_u(a) | ((unsigned int)f2h_u(b) << 16);
}
__device__ __forceinline__ float sigf_(float x) {
  return __builtin_amdgcn_rcpf(1.0f + __expf(-x));
}
__device__ __forceinline__ float tanhf_(float x) {
  return 2.0f * __builtin_amdgcn_rcpf(1.0f + __expf(-2.0f * x)) - 1.0f;
}
__device__ __forceinline__ f16x8 load_w8(const float* __restrict__ p) {
  f16x8 r;
#pragma unroll
  for (int i = 0; i < 8; ++i) r[i] = (_Float16)p[i];
  return r;
}

__global__ void init_flags(unsigned int* flags) {
  flags[blockIdx.x * 256 + threadIdx.x] = 0u;  // grid 36 -> 9216 = 144 flags * 64
}

// lgkm-only barrier: h-exchange visibility WITHOUT draining vmcnt (T4: region
// stores + xg prefetch stay in flight across step barriers; they drain only at
// the once-per-chunk publish). m201-verified pattern.
#define BARRIER_LGKM()                                              \
  do {                                                              \
    asm volatile("s_waitcnt lgkmcnt(0)" ::: "memory");              \
    __builtin_amdgcn_s_barrier();                                   \
    __builtin_amdgcn_sched_barrier(0);                              \
  } while (0)

// Publish fence: vmcnt is PER-WAVE, and tid0's release store only drains its
// own wave. Before any flag publish, ALL waves drain vmcnt, then barrier.
// Once per 32 steps -> negligible (this is what makes the per-step
// BARRIER_LGKM safe to use).
#define PUBLISH_FENCE()                                             \
  do {                                                              \
    asm volatile("s_waitcnt vmcnt(0)" ::: "memory");                \
    __builtin_amdgcn_s_barrier();                                   \
  } while (0)

// ---------------------------------------------------------------------------
// R16 = R15 (batch-4 mirror-4 rec WGs + vmcnt-free step barriers) with the
// publish race fixed: every flag publish is preceded by an all-wave vmcnt
// drain + barrier (region stores / xg loads complete before signaling).
//  - 96 rec WGs (layer = bid>>5, slice = bid&31, 4 batches each). MFMA B/C
//    cols mirrored 4x (cols c,c+4,c+8,c+12 read same LDS addr -> broadcast),
//    so each lane owns ONE h value: activation issue halves vs R14.
//  - Step loop uses s_waitcnt lgkmcnt(0) + raw s_barrier (no vmcnt drain).
//  - 16 GEMM producer WGs unchanged (batch-16), wait on 4 quarter-flags.
// Flags: fh[l][slice] = l*32+sl (l=0,1); fx[gl][bg] = 64+(gl-1)*8+bg;
//        fc[gl][slice] = 80+(gl-1)*32+sl.
// ---------------------------------------------------------------------------
__global__ __launch_bounds__(512, 2)
void lstm_pipe(const float* __restrict__ x,
               const float* __restrict__ Wih0, const float* __restrict__ Whh0,
               const float* __restrict__ bih0, const float* __restrict__ bhh0,
               const float* __restrict__ Wih1, const float* __restrict__ Whh1,
               const float* __restrict__ bih1, const float* __restrict__ bhh1,
               const float* __restrict__ Wih2, const float* __restrict__ Whh2,
               const float* __restrict__ bih2, const float* __restrict__ bhh2,
               unsigned short* __restrict__ region,   // f16 [B][T][128]
               float* __restrict__ xg,                // fp32 rings [2][8][3][XGSLOT_]
               unsigned int* __restrict__ state_h,    // [B][64] f16x2
               unsigned int* __restrict__ flags)
{
  const int bid  = blockIdx.x;
  const int tid  = threadIdx.x;
  const int lane = tid & 63;
  const int wv   = tid >> 6;    // wave 0..7
  const int n16  = lane & 15;
  const int quad = lane >> 4;

  __shared__ unsigned short smem[32 * 16 * HS_];   // 147456 B (GEMM role max)
  __shared__ int s_have;

#define WAITP(ptr_, need_, have_)                                   \
  do {                                                              \
    if ((have_) < (need_)) {                                        \
      if (tid == 0) {                                               \
        int v = (int)__hip_atomic_load(ptr_, __ATOMIC_RELAXED,      \
                                       __HIP_MEMORY_SCOPE_AGENT);   \
        while (v < (need_)) {                                       \
          __builtin_amdgcn_s_sleep(2);                              \
          v = (int)__hip_atomic_load(ptr_, __ATOMIC_RELAXED,        \
                                     __HIP_MEMORY_SCOPE_AGENT);     \
        }                                                           \
        (void)__hip_atomic_load(ptr_, __ATOMIC_ACQUIRE,             \
                                __HIP_MEMORY_SCOPE_AGENT);          \
        s_have = v;                                                 \
      }                                                             \
      __syncthreads();                                              \
      (have_) = s_have;                                             \
    }                                                               \
  } while (0)

  if (bid >= 96) {
    // ======================= GEMM producer role ==========================
    const int gi = bid - 96;
    const int gl = 1 + (gi >> 3);  // produces xg for layer gl
    const int bg = gi & 7;
    const int b8 = n16 & 7;        // swizzle key for its own batch row
    const float* Wih = (gl == 1) ? Wih1 : Wih2;
    const float* bih = (gl == 1) ? bih1 : bih2;
    const float* bhh = (gl == 1) ? bhh1 : bhh2;
    float* xgo = xg + (size_t)((gl - 1) * 8 + bg) * (XGRING_ * (size_t)XGSLOT_);
    unsigned int* fhp[4]; unsigned int* fcp[4];
#pragma unroll
    for (int q = 0; q < 4; ++q) {
      fhp[q] = &flags[((gl - 1) * 32 + 4 * bg + q) * FLAG_STRIDE_];
      fcp[q] = &flags[(80 + (gl - 1) * 32 + 4 * bg + q) * FLAG_STRIDE_];
    }
    unsigned int* fx_out = &flags[(64 + (gl - 1) * 8 + bg) * FLAG_STRIDE_];

    f16x8 wih[4][4];
#pragma unroll
    for (int j = 0; j < 4; ++j)
#pragma unroll
      for (int kc = 0; kc < 4; ++kc)
        wih[j][kc] = load_w8(Wih + (size_t)(j * 128 + 16 * wv + n16) * H_ + kc * 32 + quad * 8);
    f32x4 bias4[4];
#pragma unroll
    for (int j = 0; j < 4; ++j)
#pragma unroll
      for (int r = 0; r < 4; ++r) {
        int row = j * 128 + 16 * wv + quad * 4 + r;
        bias4[j][r] = bih[row] + bhh[row];
      }

    int haveh0 = 0, haveh1 = 0, haveh2 = 0, haveh3 = 0;
    int havec0 = 0, havec1 = 0, havec2 = 0, havec3 = 0;
    const int tt = tid >> 4, bb = tid & 15;  // staging: 1 thread per (step,row)
    const int swk = bb & 7;                  // write-side swizzle key
    for (int k = 0; k < NCHUNK_; ++k) {
      WAITP(fhp[0], k + 1, haveh0);
      WAITP(fhp[1], k + 1, haveh1);
      WAITP(fhp[2], k + 1, haveh2);
      WAITP(fhp[3], k + 1, haveh3);
      if (k >= XGRING_) {
        WAITP(fcp[0], k - (XGRING_ - 1), havec0);
        WAITP(fcp[1], k - (XGRING_ - 1), havec1);
        WAITP(fcp[2], k - (XGRING_ - 1), havec2);
        WAITP(fcp[3], k - (XGRING_ - 1), havec3);
      }
      // stage h chunk [32][16][128] -> LDS, row-swizzled
      {
        const uint4* gp = (const uint4*)(region +
            ((size_t)(bg * 16 + bb) * T_ + (size_t)(CHUNK_ * k + tt)) * H_);
        uint4* lp = (uint4*)&smem[(tt * 16 + bb) * HS_];
#pragma unroll
        for (int i = 0; i < 16; ++i) lp[i ^ swk] = gp[i];
      }
      __syncthreads();
      const int slot = k % XGRING_;
      for (int t = 0; t < CHUNK_; ++t) {
        f16x8 hi[4];
#pragma unroll
        for (int kc = 0; kc < 4; ++kc)
          hi[kc] = *(const f16x8*)&smem[(t * 16 + n16) * HS_ +
                                        ((kc * 32 + quad * 8) ^ (b8 << 3))];
        float* xp = xgo + (size_t)(slot * CHUNK_ + t) * 8192 + quad * 64 + n16 * 4;
#pragma unroll
        for (int j = 0; j < 4; ++j) {
          f32x4 a = bias4[j];
#pragma unroll
          for (int kc = 0; kc < 4; ++kc)
            a = __builtin_amdgcn_mfma_f32_16x16x32_f16(wih[j][kc], hi[kc], a, 0, 0, 0);
          *(f32x4*)(xp + (size_t)(8 * j + wv) * 256) = a;
        }
      }
      __syncthreads();  // drains stores + protects LDS reuse
      if (tid == 0)
        __hip_atomic_store(fx_out, (unsigned int)(k + 1),
                           __ATOMIC_RELEASE, __HIP_MEMORY_SCOPE_AGENT);
    }
    return;
  }

  // ========================= Recurrence role =============================
  const int layer = bid >> 5;
  const int sl    = bid & 31;          // batch-4 slice
  const int bcol  = n16 & 3;           // batch column (mirror-4)
  const int rr    = n16 >> 2;          // which acc element this lane owns
  const int batch = sl * 4 + bcol;
  const float* Whh = (layer == 0) ? Whh0 : ((layer == 1) ? Whh1 : Whh2);

  unsigned short* hstate = smem;                 // [2][4][HS_]
  unsigned short* xb = smem + 2 * 4 * HS_;       // [8][4][8] (layer 0 only)

  f16x8 whh[4][4];
#pragma unroll
  for (int j = 0; j < 4; ++j)
#pragma unroll
    for (int kc = 0; kc < 4; ++kc)
      whh[j][kc] = load_w8(Whh + (size_t)(j * 128 + 16 * wv + n16) * H_ + kc * 32 + quad * 8);

  for (int i = tid; i < (2 * 4 * HS_) / 2; i += 512) ((unsigned int*)smem)[i] = 0u;

  float cc_ = 0.f;                     // single cell value per lane
  unsigned short dh16[GRP_];
  const bool r2 = (rr & 2) != 0, r1 = (rr & 1) != 0;
  const int hcol = 16 * wv + 4 * quad + rr;         // h index this lane owns
  const int s_i  = hcol;                            // short idx within row
  const int wswz = (((s_i >> 3) ^ bcol) << 3) | (s_i & 7);  // swizzled short idx
  unsigned int* fh_out = (layer < 2) ? &flags[(layer * 32 + sl) * FLAG_STRIDE_] : nullptr;

  if (layer == 0) {
    // ------------------------- layer 0 ---------------------------------
    f32x4 bias4[4];
#pragma unroll
    for (int j = 0; j < 4; ++j)
#pragma unroll
      for (int r = 0; r < 4; ++r) {
        int row = j * 128 + 16 * wv + quad * 4 + r;
        bias4[j][r] = bih0[row] + bhh0[row];
      }
    f16x8 wx[4];
#pragma unroll
    for (int j = 0; j < 4; ++j)
#pragma unroll
      for (int i = 0; i < 8; ++i) wx[j][i] = (_Float16)0.f;
    if (quad == 0) {
#pragma unroll
      for (int j = 0; j < 4; ++j) {
        const float* p = Wih0 + (size_t)(j * 128 + 16 * wv + n16) * IN_;
#pragma unroll
        for (int i = 0; i < IN_; ++i) wx[j][i] = (_Float16)p[i];
      }
    }
    const int sn_x = tid & 3, st_x = tid >> 2;  // staging map (tid<32)
    float xraw[6];
    __syncthreads();   // zeros visible
    if (tid < 32) {
      const float* xp = x + ((size_t)(sl * 4 + sn_x) * T_ + st_x) * IN_;
#pragma unroll
      for (int i = 0; i < IN_; ++i) xraw[i] = xp[i];
      uint4 xr4;
      xr4.x = pack2(xraw[0], xraw[1]); xr4.y = pack2(xraw[2], xraw[3]);
      xr4.z = pack2(xraw[4], xraw[5]); xr4.w = 0u;
      *(uint4*)&xb[(st_x * 4 + sn_x) * 8] = xr4;
    }
    __syncthreads();

    for (int g = 0; g < NGRP_; ++g) {
      if (tid < 32 && g + 1 < NGRP_) {
        const float* xp = x + ((size_t)(sl * 4 + sn_x) * T_ + (8 * (g + 1) + st_x)) * IN_;
#pragma unroll
        for (int i = 0; i < IN_; ++i) xraw[i] = xp[i];   // drains at pack, not per step
      }
#pragma unroll
      for (int s = 0; s < GRP_; ++s) {
        const int rp = s & 1, wp = rp ^ 1;
        f16x8 hs[4];
#pragma unroll
        for (int kc = 0; kc < 4; ++kc)
          hs[kc] = *(const f16x8*)&hstate[(rp * 4 + bcol) * HS_ +
                                          ((kc * 32 + quad * 8) ^ (bcol << 3))];
        f16x8 xi;
#pragma unroll
        for (int i = 0; i < 8; ++i) xi[i] = (_Float16)0.f;
        if (quad == 0) xi = *(const f16x8*)&xb[(s * 4 + bcol) * 8];
        f32x4 acc[4];
#pragma unroll
        for (int j = 0; j < 4; ++j) {
          f32x4 a = __builtin_amdgcn_mfma_f32_16x16x32_f16(wx[j], xi, bias4[j], 0, 0, 0);
#pragma unroll
          for (int kc = 0; kc < 4; ++kc)
            a = __builtin_amdgcn_mfma_f32_16x16x32_f16(whh[j][kc], hs[kc], a, 0, 0, 0);
          acc[j] = a;
        }
        float g4[4];
#pragma unroll
        for (int j = 0; j < 4; ++j) {
          float t0 = r2 ? acc[j][2] : acc[j][0];
          float t1 = r2 ? acc[j][3] : acc[j][1];
          g4[j] = r1 ? t1 : t0;
        }
        float i_ = sigf_(g4[0]), f_ = sigf_(g4[1]), t_ = tanhf_(g4[2]), o_ = sigf_(g4[3]);
        cc_ = f_ * cc_ + i_ * t_;
        float h_ = o_ * tanhf_(cc_);
        unsigned short uh = f2h_u(h_);
        dh16[s] = uh;
        hstate[(wp * 4 + bcol) * HS_ + wswz] = uh;
        BARRIER_LGKM();
      }
      // deferred h stores (stay in flight until chunk publish) + x staging
#pragma unroll
      for (int s = 0; s < GRP_; ++s)
        region[((size_t)batch * T_ + (8 * g + s)) * H_ + hcol] = dh16[s];
      if (tid < 32 && g + 1 < NGRP_) {
        uint4 xr4;
        xr4.x = pack2(xraw[0], xraw[1]); xr4.y = pack2(xraw[2], xraw[3]);
        xr4.z = pack2(xraw[4], xraw[5]); xr4.w = 0u;
        *(uint4*)&xb[(st_x * 4 + sn_x) * 8] = xr4;
      }
      BARRIER_LGKM();  // publishes xb; region stores stay in flight
      if ((g & 3) == 3) {
        PUBLISH_FENCE();  // ALL waves drain region stores before signal
        if (tid == 0)
          __hip_atomic_store(fh_out, (unsigned int)((g >> 2) + 1),
                             __ATOMIC_RELEASE, __HIP_MEMORY_SCOPE_AGENT);
      }
    }
  } else {
    // ----------------------- layers 1 and 2 ----------------------------
    const int bg = sl >> 2;
    const float* xgi = xg + (size_t)((layer - 1) * 8 + bg) * (XGRING_ * (size_t)XGSLOT_);
    const int xcol = (sl & 3) * 4 + bcol;   // batch column in the 16-wide tile
    f32x4 xr[2][4];
    auto load_xg = [&](int t, int buf) {
      int slot = (t >> 5) % XGRING_;
      const float* p = xgi + (size_t)(slot * CHUNK_ + (t & 31)) * 8192
                       + (size_t)wv * 256 + quad * 64 + xcol * 4;
      xr[buf][0] = *(const f32x4*)(p);
      xr[buf][1] = *(const f32x4*)(p + 2048);
      xr[buf][2] = *(const f32x4*)(p + 4096);
      xr[buf][3] = *(const f32x4*)(p + 6144);
    };
    unsigned int* fx_in  = &flags[(64 + (layer - 1) * 8 + bg) * FLAG_STRIDE_];
    unsigned int* fc_out = &flags[(80 + (layer - 1) * 32 + sl) * FLAG_STRIDE_];
    int have_x = 0;
    __syncthreads();  // hstate zeros visible

    for (int g = 0; g < NGRP_; ++g) {
      if ((g & 3) == 0) {
        int c = g >> 2;
        WAITP(fx_in, c + 1, have_x);
        load_xg(32 * c, 0);
        load_xg(32 * c + 1, 1);
      }
#pragma unroll
      for (int s = 0; s < GRP_; ++s) {
        const int t = 8 * g + s;
        const int rp = s & 1, wp = rp ^ 1;
        f16x8 hs[4];
#pragma unroll
        for (int kc = 0; kc < 4; ++kc)
          hs[kc] = *(const f16x8*)&hstate[(rp * 4 + bcol) * HS_ +
                                          ((kc * 32 + quad * 8) ^ (bcol << 3))];
        f32x4 ci[4];
#pragma unroll
        for (int j = 0; j < 4; ++j) ci[j] = xr[s & 1][j];
        if (!(((g & 3) == 3) && s >= 6)) load_xg(t + 2, s & 1);
        f32x4 acc[4];
#pragma unroll
        for (int j = 0; j < 4; ++j) {
          f32x4 a = ci[j];
#pragma unroll
          for (int kc = 0; kc < 4; ++kc)
            a = __builtin_amdgcn_mfma_f32_16x16x32_f16(whh[j][kc], hs[kc], a, 0, 0, 0);
          acc[j] = a;
        }
        float g4[4];
#pragma unroll
        for (int j = 0; j < 4; ++j) {
          float t0 = r2 ? acc[j][2] : acc[j][0];
          float t1 = r2 ? acc[j][3] : acc[j][1];
          g4[j] = r1 ? t1 : t0;
        }
        float i_ = sigf_(g4[0]), f_ = sigf_(g4[1]), t_ = tanhf_(g4[2]), o_ = sigf_(g4[3]);
        cc_ = f_ * cc_ + i_ * t_;
        float h_ = o_ * tanhf_(cc_);
        unsigned short uh = f2h_u(h_);
        dh16[s] = uh;
        hstate[(wp * 4 + bcol) * HS_ + wswz] = uh;
        BARRIER_LGKM();
      }
      if (layer == 1) {
#pragma unroll
        for (int s = 0; s < GRP_; ++s)
          region[((size_t)batch * T_ + (8 * g + s)) * H_ + hcol] = dh16[s];
      }
      if ((g & 3) == 3) {
        // Drain region stores (layer1) AND this chunk's xg loads (both
        // layers) in ALL waves before signaling; then publish.
        PUBLISH_FENCE();
        if (tid == 0) {
          unsigned int cdone = (unsigned int)((g >> 2) + 1);
          if (layer == 1)
            __hip_atomic_store(fh_out, cdone, __ATOMIC_RELEASE, __HIP_MEMORY_SCOPE_AGENT);
          __hip_atomic_store(fc_out, cdone, __ATOMIC_RELEASE, __HIP_MEMORY_SCOPE_AGENT);
        }
      }
    }
    if (layer == 2)
      ((unsigned short*)state_h)[(size_t)batch * 128 + hcol] = dh16[GRP_ - 1];
  }
#undef WAITP
}

// ---------------------------------------------------------------------------
__global__ void head_kernel(const unsigned int* __restrict__ state_h,
                            const float* __restrict__ Wout,
                            const float* __restrict__ bout,
                            float* __restrict__ out)
{
  int b = threadIdx.x;  // 128 threads, 1 block
  float s = bout[0];
  for (int j = 0; j < 64; ++j) {
    unsigned int p = state_h[b * 64 + j];
    union { unsigned short u; _Float16 h; } lo, hi;
    lo.u = (unsigned short)(p & 0xffffu);
    hi.u = (unsigned short)(p >> 16);
    s += (float)lo.h * Wout[2 * j] + (float)hi.h * Wout[2 * j + 1];
  }
  out[b] = s;
}

// ---------------------------------------------------------------------------
extern "C" void kernel_launch(void* const* d_in, const int* in_sizes, int n_in,
                              void* d_out, int out_size, void* d_ws, size_t ws_size,
                              hipStream_t stream)
{
  const float* x = (const float*)d_in[0];
  const float* Wih[3] = {(const float*)d_in[1], (const float*)d_in[5], (const float*)d_in[9]};
  const float* Whh[3] = {(const float*)d_in[2], (const float*)d_in[6], (const float*)d_in[10]};
  const float* bih[3] = {(const float*)d_in[3], (const float*)d_in[7], (const float*)d_in[11]};
  const float* bhh[3] = {(const float*)d_in[4], (const float*)d_in[8], (const float*)d_in[12]};
  const float* Wout = (const float*)d_in[13];
  const float* bout = (const float*)d_in[14];
  float* out = (float*)d_out;

  char* ws = (char*)d_ws;
  size_t off = 0;
  unsigned short* region = (unsigned short*)(ws + off); off += (size_t)B_ * T_ * H_ * 2;   // 64 MiB
  float* xg = (float*)(ws + off);                       off += (size_t)16 * XGRING_ * XGSLOT_ * 4;  // 48 MiB
  unsigned int* state_h  = (unsigned int*)(ws + off);   off += (size_t)B_ * 64 * 4;
  off = (off + 255) & ~(size_t)255;
  unsigned int* flags    = (unsigned int*)(ws + off);   off += NFLAGS_ * FLAG_STRIDE_ * 4;

  init_flags<<<36, 256, 0, stream>>>(flags);
  lstm_pipe<<<112, 512, 0, stream>>>(x,
      Wih[0], Whh[0], bih[0], bhh[0],
      Wih[1], Whh[1], bih[1], bhh[1],
      Wih[2], Whh[2], bih[2], bhh[2],
      region, xg, state_h, flags);
  head_kernel<<<1, 128, 0, stream>>>(state_h, Wout, bout, out);
}